// Round 1
// baseline (396.383 us; speedup 1.0000x reference)
//
#include <hip/hip_runtime.h>

// Shapes fixed by the reference: N=2, C=32, H=W=64, O=32, K=3, stride=1, pad=1.
// out[n][o][oh][ow] = relu( sum_{c,kh,kw} feat[n,c,oh+kh-1,ow+kw-1]
//                                        * filt[n, l, c*9+kh*3+kw, o] ),  l = oh*W+ow
// filters slice for fixed (n,l) is [288,32] row-major contiguous (9216 floats).

#define C_     32
#define H_     64
#define W_     64
#define O_     32
#define CKK_   288
#define L_     (H_ * W_)

__global__ __launch_bounds__(256) void convfilt_kernel(
    const float* __restrict__ features,
    const float* __restrict__ filters,
    float* __restrict__ out)
{
    const int loc = blockIdx.x;            // n*L + l
    const int n   = loc / L_;
    const int l   = loc % L_;
    const int oh  = l / W_;
    const int ow  = l % W_;
    const int t   = threadIdx.x;           // 0..255

    __shared__ float s_feat[CKK_];
    __shared__ float s_red[4][O_];

    // ---- stage the 288-element feature patch (with zero pad) into LDS ----
    for (int idx = t; idx < CKK_; idx += 256) {
        const int c  = idx / 9;
        const int r  = idx % 9;
        const int kh = r / 3;
        const int kw = r % 3;
        const int ih = oh + kh - 1;
        const int iw = ow + kw - 1;
        float v = 0.0f;
        if (ih >= 0 && ih < H_ && iw >= 0 && iw < W_)
            v = features[((n * C_ + c) * H_ + ih) * W_ + iw];
        s_feat[idx] = v;
    }
    __syncthreads();

    // ---- stream the [288,32] filter slice: 9 x 256 float4, fully coalesced ----
    // flat float index e = (i*256 + t)*4 ; k = e/32 = i*32 + t/8 ; o_base = (t%8)*4
    const float4* __restrict__ fptr =
        (const float4*)(filters + (size_t)loc * (CKK_ * O_));

    float acc0 = 0.f, acc1 = 0.f, acc2 = 0.f, acc3 = 0.f;
#pragma unroll
    for (int i = 0; i < 9; ++i) {
        const float4 f  = fptr[i * 256 + t];
        const float  fv = s_feat[(i * 256 + t) >> 3];
        acc0 = fmaf(f.x, fv, acc0);
        acc1 = fmaf(f.y, fv, acc1);
        acc2 = fmaf(f.z, fv, acc2);
        acc3 = fmaf(f.w, fv, acc3);
    }

    // ---- reduce across the 8 lanes per wave that share the same o-group ----
    // lanes with lane%8 equal hold the same 4 output channels; tree over 8/16/32
#pragma unroll
    for (int s = 8; s < 64; s <<= 1) {
        acc0 += __shfl_down(acc0, s);
        acc1 += __shfl_down(acc1, s);
        acc2 += __shfl_down(acc2, s);
        acc3 += __shfl_down(acc3, s);
    }

    const int wave = t >> 6;   // 0..3
    const int lane = t & 63;
    if (lane < 8) {
        const int ob = lane * 4;
        s_red[wave][ob + 0] = acc0;
        s_red[wave][ob + 1] = acc1;
        s_red[wave][ob + 2] = acc2;
        s_red[wave][ob + 3] = acc3;
    }
    __syncthreads();

    // ---- final cross-wave reduction + ReLU + store (coalesced over l? no: over o) ----
    if (t < O_) {
        float r = s_red[0][t] + s_red[1][t] + s_red[2][t] + s_red[3][t];
        r = fmaxf(r, 0.0f);
        out[((size_t)n * O_ + t) * L_ + l] = r;   // out[n][o][oh][ow]
    }
}

extern "C" void kernel_launch(void* const* d_in, const int* in_sizes, int n_in,
                              void* d_out, int out_size, void* d_ws, size_t ws_size,
                              hipStream_t stream)
{
    const float* features = (const float*)d_in[0];   // [N, C, H, W]
    const float* filters  = (const float*)d_in[1];   // [N, L, Ckk, O]
    float* out            = (float*)d_out;           // [N, O, H, W]

    const int N = in_sizes[0] / (C_ * H_ * W_);      // = 2
    const int grid = N * L_;                         // 8192 blocks

    convfilt_kernel<<<grid, 256, 0, stream>>>(features, filters, out);
}

// Round 2
// 375.203 us; speedup vs baseline: 1.0565x; 1.0565x over previous
//
#include <hip/hip_runtime.h>

// Shapes fixed by the reference: N=2, C=32, H=W=64, O=32, K=3, stride=1, pad=1.
// out[n][o][oh][ow] = relu( sum_k feat_patch[k] * filt[n, l, k, o] ), l = oh*W+ow
// filters slice for fixed (n,l): [288,32] row-major contiguous = 9216 floats (36 KB).
//
// Structure: ONE WAVE PER LOCATION (4 waves/block, fully independent).
//  - wave gathers its 288-float feature patch into a private LDS segment
//  - 36 x float4 nontemporal loads stream the filter slice (lane covers
//    flat float4 index j*64+lane -> k = 8j + lane/8, o = 4*(lane%8)..+3)
//  - 3-step shuffle reduction over the 8 k-clusters, ReLU, store.
// Filters are 302 MB read-once => hard memory-bound; floor ~48 us at 6.3 TB/s.

#define C_   32
#define H_   64
#define W_   64
#define O_   32
#define CKK_ 288
#define L_   (H_ * W_)

typedef float vf4 __attribute__((ext_vector_type(4)));

__global__ __launch_bounds__(256) void convfilt_kernel(
    const float* __restrict__ features,
    const float* __restrict__ filters,
    float* __restrict__ out)
{
    const int wave = threadIdx.x >> 6;
    const int lane = threadIdx.x & 63;
    const int loc  = blockIdx.x * 4 + wave;     // n*L + l, one wave per location

    const int n  = loc >> 12;                   // / 4096
    const int l  = loc & (L_ - 1);
    const int oh = l >> 6;
    const int ow = l & (W_ - 1);

    __shared__ float sf[4][CKK_];
    float* __restrict__ s = sf[wave];           // wave-private segment

    // ---- gather the 288-element feature patch (zero pad) into LDS ----
    #pragma unroll
    for (int q = 0; q < 5; ++q) {
        const int e = q * 64 + lane;            // q=4: only lanes <32 active
        if (e < CKK_) {
            const int c  = e / 9;
            const int r  = e % 9;
            const int ih = oh + (r / 3) - 1;
            const int iw = ow + (r % 3) - 1;
            float v = 0.0f;
            if ((unsigned)ih < (unsigned)H_ && (unsigned)iw < (unsigned)W_)
                v = features[((n * C_ + c) * H_ + ih) * W_ + iw];
            s[e] = v;
        }
    }
    __syncthreads();   // orders the wave-private LDS writes vs reads (cheap, once)

    // ---- stream the [288,32] filter slice: 36 x 64-lane float4, coalesced ----
    const vf4* __restrict__ fp =
        (const vf4*)(filters + (size_t)loc * (CKK_ * O_));
    const int g = lane >> 3;                    // k-cluster: k = 8j + g

    float a0 = 0.f, a1 = 0.f, a2 = 0.f, a3 = 0.f;
    #pragma unroll
    for (int j = 0; j < 36; ++j) {
        const vf4  f  = __builtin_nontemporal_load(fp + j * 64 + lane);
        const float fv = s[j * 8 + g];          // broadcast per 8-lane cluster
        a0 = fmaf(f.x, fv, a0);
        a1 = fmaf(f.y, fv, a1);
        a2 = fmaf(f.z, fv, a2);
        a3 = fmaf(f.w, fv, a3);
    }

    // ---- reduce over the 8 clusters (lanes m, m+8, ..., m+56 share o-group) ----
    #pragma unroll
    for (int st = 8; st < 64; st <<= 1) {
        a0 += __shfl_down(a0, st);
        a1 += __shfl_down(a1, st);
        a2 += __shfl_down(a2, st);
        a3 += __shfl_down(a3, st);
    }

    // ---- ReLU + store: lane m (<8) owns o = 4m..4m+3 ----
    if (lane < 8) {
        float* op = out + ((size_t)n * O_ + lane * 4) * L_ + l;
        op[0 * L_] = fmaxf(a0, 0.f);
        op[1 * L_] = fmaxf(a1, 0.f);
        op[2 * L_] = fmaxf(a2, 0.f);
        op[3 * L_] = fmaxf(a3, 0.f);
    }
}

extern "C" void kernel_launch(void* const* d_in, const int* in_sizes, int n_in,
                              void* d_out, int out_size, void* d_ws, size_t ws_size,
                              hipStream_t stream)
{
    const float* features = (const float*)d_in[0];   // [N, C, H, W]
    const float* filters  = (const float*)d_in[1];   // [N, L, Ckk, O]
    float* out            = (float*)d_out;           // [N, O, H, W]

    const int N     = in_sizes[0] / (C_ * H_ * W_);  // = 2
    const int total = N * L_;                        // 8192 locations
    const int grid  = total / 4;                     // 4 waves (locations) per block

    convfilt_kernel<<<grid, 256, 0, stream>>>(features, filters, out);
}